// Round 6
// baseline (79.909 us; speedup 1.0000x reference)
//
#include <hip/hip_runtime.h>
#include <hip/hip_bf16.h>
#include <stdint.h>

// CACProjector: logits = x @ W^T ; dist = sqrt(max(||row||^2 - 2*A*logit + A^2, 0))
// Round 6: round-5 plan with the f32x4/float4 type mismatch fixed (ar[] is ext_vector).
// Fused x f32->bf16 in GEMM (reg-staged A), B via global_load_lds, tiny W-cvt,
// XCD-matched dist mapping.

#define M_DIM 16384
#define N_DIM 1024
#define K_DIM 768
#define ALPHA_F 10.0f

typedef __bf16 bf16x8 __attribute__((ext_vector_type(8)));
typedef float f32x4 __attribute__((ext_vector_type(4)));
typedef const __attribute__((address_space(1))) void* gas_ptr;
typedef __attribute__((address_space(3))) void* las_ptr;

#define WAITV(N) asm volatile("s_waitcnt vmcnt(" #N ")" ::: "memory")
#define LGKM0 asm volatile("s_waitcnt lgkmcnt(0)" ::: "memory")
#define PRIO1 __builtin_amdgcn_s_setprio(1)
#define PRIO0 __builtin_amdgcn_s_setprio(0)

static __device__ __forceinline__ void bar() {
  asm volatile("" ::: "memory");
  __builtin_amdgcn_s_barrier();
  asm volatile("" ::: "memory");
}

// ---------------- W fp32 -> bf16 (tiny: 3MB read) ----------------
__global__ __launch_bounds__(256) void cvt_w_kernel(const float* __restrict__ in,
                                                    unsigned short* __restrict__ out) {
  int i = blockIdx.x * 256 + threadIdx.x;  // grid 768 -> exactly N_DIM*K_DIM/4
  f32x4 v = reinterpret_cast<const f32x4*>(in)[i];
  union { __bf16 h[4]; ushort4 u; } p;
  p.h[0] = (__bf16)v[0]; p.h[1] = (__bf16)v[1];
  p.h[2] = (__bf16)v[2]; p.h[3] = (__bf16)v[3];
  reinterpret_cast<ushort4*>(out)[i] = p.u;
}

// ---------------- MFMA quadrant helper ----------------
template <int MI0, int NI0>
__device__ __forceinline__ void mfma_quad(f32x4 (&acc)[8][4], bf16x8 (&af)[8][2],
                                          bf16x8 (&bq)[4][2]) {
#pragma unroll
  for (int mi = 0; mi < 4; ++mi)
#pragma unroll
    for (int ni = 0; ni < 2; ++ni)
#pragma unroll
      for (int kk = 0; kk < 2; ++kk)
        acc[MI0 + mi][NI0 + ni] = __builtin_amdgcn_mfma_f32_16x16x32_bf16(
            af[MI0 + mi][kk], bq[NI0 + ni][kk], acc[MI0 + mi][NI0 + ni], 0, 0, 0);
}

// ---------------- 256x256 bf16 GEMM with fused A-conversion ----------------
// 512 threads = 8 waves (2M x 4N), per-wave 128x64. LDS [2][4][128*64] = 128 KiB.
// A path (reg-staged): p0 issue 8x dwordx4 f32 of A(kt+2); p2/p3 cvt+ds_write.
// B path: global_load_lds width-16, linear dest slot=t / t+512, pre-swizzled src.
// WAITV(0) at p3 gates B(kt+1); compiler auto-drains the A-f32 loads at p2/p3 use.
// LGKM0 before bars after ds_writes (raw s_barrier does not drain lgkm).
__global__ __launch_bounds__(512, 2) void gemm_fused_kernel(
    const float* __restrict__ X,            // 16384 x 768 f32
    const unsigned short* __restrict__ B,   // 1024 x 768 bf16 bits
    float* __restrict__ C) {                // 16384 x 1024 f32
  __shared__ __align__(16) unsigned short lds[2][4][128 * 64];

  const int t = threadIdx.x;
  const int lane = t & 63;
  const int w = t >> 6;
  const int wr = w >> 2;  // M-half
  const int wc = w & 3;   // N quarter

  // T1: XCD swizzle (nwg=256); XCD x owns rows [x*2048, x*2048+2048)
  int bid = blockIdx.x;
  int swz = (bid & 7) * 32 + (bid >> 3);
  int tn = swz & 3;
  int tm = swz >> 2;

  const float* Xbase = X + (size_t)tm * 256 * K_DIM;
  const unsigned short* Bbase = B + (size_t)tn * 256 * K_DIM;

  // staging slots: slot = t and t+512 per [128 row][8 slot] half (lane*16 rule)
  const int s0 = t, s1 = t + 512;
  const int r0 = s0 >> 3, c0 = s0 & 7;
  const int r1 = s1 >> 3, c1 = s1 & 7;
  const int cc0 = c0 ^ (r0 & 7);  // pre-swizzled source col16
  const int cc1 = c1 ^ (r1 & 7);

  auto stageB = [&](int buf, int hf, int kt) {
    const unsigned short* gb = Bbase + (size_t)(hf * 128) * K_DIM + kt * 64;
    unsigned short* lb = &lds[buf][2 + hf][0];
    __builtin_amdgcn_global_load_lds((gas_ptr)(gb + (size_t)r0 * K_DIM + cc0 * 8),
                                     (las_ptr)(lb + s0 * 8), 16, 0, 0);
    __builtin_amdgcn_global_load_lds((gas_ptr)(gb + (size_t)r1 * K_DIM + cc1 * 8),
                                     (las_ptr)(lb + s1 * 8), 16, 0, 0);
  };

  // A register staging: ar[0..3] = half A0 (slots s0,s1), ar[4..7] = half A1
  f32x4 ar[8];
  auto issueA = [&](int kt) {
    const float* g0 = Xbase + (size_t)r0 * K_DIM + kt * 64 + cc0 * 8;
    const float* g1 = Xbase + (size_t)r1 * K_DIM + kt * 64 + cc1 * 8;
    const float* g2 = Xbase + (size_t)(128 + r0) * K_DIM + kt * 64 + cc0 * 8;
    const float* g3 = Xbase + (size_t)(128 + r1) * K_DIM + kt * 64 + cc1 * 8;
    ar[0] = ((const f32x4*)g0)[0]; ar[1] = ((const f32x4*)g0)[1];
    ar[2] = ((const f32x4*)g1)[0]; ar[3] = ((const f32x4*)g1)[1];
    ar[4] = ((const f32x4*)g2)[0]; ar[5] = ((const f32x4*)g2)[1];
    ar[6] = ((const f32x4*)g3)[0]; ar[7] = ((const f32x4*)g3)[1];
  };
  auto cvt8 = [&](f32x4 a, f32x4 b) -> bf16x8 {
    union { __bf16 h[8]; bf16x8 v; } p;
    p.h[0] = (__bf16)a[0]; p.h[1] = (__bf16)a[1];
    p.h[2] = (__bf16)a[2]; p.h[3] = (__bf16)a[3];
    p.h[4] = (__bf16)b[0]; p.h[5] = (__bf16)b[1];
    p.h[6] = (__bf16)b[2]; p.h[7] = (__bf16)b[3];
    return p.v;
  };
  auto writeA0 = [&](int buf) {  // half 0 <- ar[0..3]
    *(bf16x8*)(&lds[buf][0][0] + s0 * 8) = cvt8(ar[0], ar[1]);
    *(bf16x8*)(&lds[buf][0][0] + s1 * 8) = cvt8(ar[2], ar[3]);
  };
  auto writeA1 = [&](int buf) {  // half 1 <- ar[4..7]
    *(bf16x8*)(&lds[buf][1][0] + s0 * 8) = cvt8(ar[4], ar[5]);
    *(bf16x8*)(&lds[buf][1][0] + s1 * 8) = cvt8(ar[6], ar[7]);
  };

  f32x4 acc[8][4] = {};
  bf16x8 af[8][2];
  bf16x8 bq[4][2];

  auto ld_a = [&](int buf, int mi, int kk) -> bf16x8 {
    int row = mi * 16 + (lane & 15);
    int cs = (kk * 4 + (lane >> 4)) ^ (row & 7);
    return *(const bf16x8*)(&lds[buf][wr][0] + row * 64 + cs * 8);
  };
  auto ld_b = [&](int buf, int ni, int kk) -> bf16x8 {
    int row = (wc & 1) * 64 + ni * 16 + (lane & 15);
    int cs = (kk * 4 + (lane >> 4)) ^ (row & 7);
    return *(const bf16x8*)(&lds[buf][2 + (wc >> 1)][0] + row * 64 + cs * 8);
  };
  auto loadA = [&](int buf, int m0) {
#pragma unroll
    for (int mi = 0; mi < 4; ++mi) {
      af[m0 + mi][0] = ld_a(buf, m0 + mi, 0);
      af[m0 + mi][1] = ld_a(buf, m0 + mi, 1);
    }
  };
  auto loadB = [&](int buf, int n0) {
#pragma unroll
    for (int ni = 0; ni < 2; ++ni) {
      bq[n0 + ni][0] = ld_b(buf, n0 + ni, 0);
      bq[n0 + ni][1] = ld_b(buf, n0 + ni, 1);
    }
  };

  // Prologue: A(0)->buf0, A(1)->buf1 via reg path; B(0) via gll; drain all.
  issueA(0);
  stageB(0, 0, 0); stageB(0, 1, 0);
  writeA0(0); writeA1(0);
  issueA(1);
  writeA0(1); writeA1(1);
  LGKM0;
  WAITV(0);
  bar();

#pragma unroll 1
  for (int kt = 0; kt < 10; ++kt) {
    const int buf = kt & 1, nbuf = buf ^ 1;
    // p0: reads A[0..3],B[0..1](kt); issue A-f32(kt+2); gll B0(kt+1)
    issueA(kt + 2);
    stageB(nbuf, 0, kt + 1);
    loadA(buf, 0); loadB(buf, 0);
    bar(); PRIO1; mfma_quad<0, 0>(acc, af, bq); PRIO0; bar();
    // p1: reads A[4..7]; gll B1(kt+1)
    stageB(nbuf, 1, kt + 1);
    loadA(buf, 4);
    bar(); PRIO1; mfma_quad<4, 0>(acc, af, bq); PRIO0; bar();
    // p2: reads B[2..3]; cvt+write A0(kt+2) (A(kt) reads already retired)
    loadB(buf, 2);
    writeA0(buf);
    LGKM0;
    bar(); PRIO1; mfma_quad<0, 2>(acc, af, bq); PRIO0; bar();
    // p3: cvt+write A1(kt+2); gate B(kt+1) landed
    writeA1(buf);
    LGKM0;
    WAITV(0);
    bar(); PRIO1; mfma_quad<4, 2>(acc, af, bq); PRIO0; bar();
  }

  // kt = 10 (buf 0): stage B(11) only
  stageB(1, 0, 11);
  loadA(0, 0); loadB(0, 0);
  bar(); PRIO1; mfma_quad<0, 0>(acc, af, bq); PRIO0; bar();
  stageB(1, 1, 11);
  loadA(0, 4);
  bar(); PRIO1; mfma_quad<4, 0>(acc, af, bq); PRIO0; bar();
  loadB(0, 2);
  bar(); PRIO1; mfma_quad<0, 2>(acc, af, bq); PRIO0; bar();
  WAITV(0);
  bar(); PRIO1; mfma_quad<4, 2>(acc, af, bq); PRIO0;
  bar();
  // kt = 11 (buf 1): everything landed, no further LDS writes
  loadA(1, 0); loadB(1, 0);
  loadA(1, 4); loadB(1, 2);
  PRIO1;
  mfma_quad<0, 0>(acc, af, bq);
  mfma_quad<4, 0>(acc, af, bq);
  mfma_quad<0, 2>(acc, af, bq);
  mfma_quad<4, 2>(acc, af, bq);
  PRIO0;

  // C write
  float* Cb = C + ((size_t)tm * 256 + wr * 128) * N_DIM + tn * 256 + wc * 64;
#pragma unroll
  for (int mi = 0; mi < 8; ++mi)
#pragma unroll
    for (int ni = 0; ni < 4; ++ni) {
      int col = ni * 16 + (lane & 15);
      int row0 = mi * 16 + ((lane >> 4) << 2);
      f32x4 v = acc[mi][ni];
#pragma unroll
      for (int r = 0; r < 4; ++r)
        Cb[(size_t)(row0 + r) * N_DIM + col] = v[r];
    }
}

// ---------------- distance epilogue: XCD-matched reversed row mapping ----------------
__global__ __launch_bounds__(256) void dist_kernel(const float* __restrict__ logits,
                                                   float* __restrict__ dist) {
  __shared__ float wsum[4];
  const int bid = blockIdx.x;
  // GEMM's XCD x wrote rows [x*2048, x*2048+2048); read that XCD's rows newest-first.
  const int row = (bid & 7) * 2048 + (2047 - (bid >> 3));
  const int t = threadIdx.x;
  const f32x4* lr = reinterpret_cast<const f32x4*>(logits + (size_t)row * N_DIM);
  f32x4 v = lr[t];
  float ss = v[0] * v[0] + v[1] * v[1] + v[2] * v[2] + v[3] * v[3];
#pragma unroll
  for (int m = 32; m >= 1; m >>= 1) ss += __shfl_xor(ss, m, 64);
  if ((t & 63) == 0) wsum[t >> 6] = ss;
  __syncthreads();
  float sq = wsum[0] + wsum[1] + wsum[2] + wsum[3];
  const float a2 = ALPHA_F * ALPHA_F;
  f32x4 d;
#pragma unroll
  for (int j = 0; j < 4; ++j)
    d[j] = sqrtf(fmaxf(sq - 2.0f * ALPHA_F * v[j] + a2, 0.0f));
  reinterpret_cast<f32x4*>(dist + (size_t)row * N_DIM)[t] = d;
}

extern "C" void kernel_launch(void* const* d_in, const int* in_sizes, int n_in,
                              void* d_out, int out_size, void* d_ws, size_t ws_size,
                              hipStream_t stream) {
  const float* x = (const float*)d_in[0];  // 16384 x 768
  const float* W = (const float*)d_in[1];  // 1024 x 768
  float* logits = (float*)d_out;
  float* dist = logits + (size_t)M_DIM * N_DIM;

  unsigned short* Wb = (unsigned short*)d_ws;  // 1.5 MB

  cvt_w_kernel<<<N_DIM * K_DIM / 4 / 256, 256, 0, stream>>>(W, Wb);
  gemm_fused_kernel<<<(M_DIM / 256) * (N_DIM / 256), 512, 0, stream>>>(x, Wb, logits);
  dist_kernel<<<M_DIM, 256, 0, stream>>>(logits, dist);
}